// Round 1
// baseline (849.158 us; speedup 1.0000x reference)
//
#include <hip/hip_runtime.h>
#include <math.h>

#define NROWS 32768
#define NEMBD 2048
#define NEXP  64
#define RPB   64            // rows per block (one per lane-column)
#define NWAVE 8             // waves per block = split-K factor
#define KSLICE (NEMBD / NWAVE)   // 256
#define KCH   16            // k-chunk: one s_load_dwordx16 of x per row
#define PAD   67            // odd pad -> 2-way (free) LDS bank aliasing

__global__ __launch_bounds__(512, 4)
void router_kernel(const float* __restrict__ x,
                   const float* __restrict__ W,
                   float* __restrict__ out)
{
    float* out_idx = out;                 // [32768][2] indices (as float)
    float* out_wgt = out + 2 * NROWS;     // [32768][2] softmax weights
    float* out_log = out + 4 * NROWS;     // [32768][64] logits

    const int tid  = threadIdx.x;
    const int lane = tid & 63;                                   // expert id
    const int wv   = __builtin_amdgcn_readfirstlane(tid >> 6);   // k-slice id (SGPR)
    const int rowbase = blockIdx.x * RPB;

    // x pointer is wave-uniform: depends only on blockIdx + wave id + loop vars
    const float* __restrict__ xbase = x + (size_t)rowbase * NEMBD + wv * KSLICE;
    // W pointer is per-lane (expert = lane); W is tiny and L2-resident
    const float* __restrict__ Wl    = W + (size_t)lane * NEMBD + wv * KSLICE;

    float acc[RPB];
#pragma unroll
    for (int t = 0; t < RPB; ++t) acc[t] = 0.f;

#pragma unroll 1
    for (int k0 = 0; k0 < KSLICE; k0 += KCH) {
        // W chunk for this lane's expert -> VGPRs, reused across all 64 rows
        float wreg[KCH];
#pragma unroll
        for (int j = 0; j < KCH; j += 4) {
            float4 v = *reinterpret_cast<const float4*>(Wl + k0 + j);
            wreg[j+0] = v.x; wreg[j+1] = v.y; wreg[j+2] = v.z; wreg[j+3] = v.w;
        }
        // 64 rows x 16 k: x values are wave-uniform -> scalar loads,
        // inner op is v_fmac_f32 acc, s_x, v_w  (1 VALU instr per MAC)
#pragma unroll
        for (int t = 0; t < RPB; ++t) {
            const float* xr = xbase + (size_t)t * NEMBD + k0;
            float a = acc[t];
#pragma unroll
            for (int j = 0; j < KCH; ++j)
                a = fmaf(xr[j], wreg[j], a);
            acc[t] = a;
        }
    }

    // ---- cross-wave (split-K) reduction through LDS, 4 row-group rounds ----
    __shared__ float stage[NWAVE][16][PAD];   // 33.5 KB
    __shared__ float lsmem[RPB][PAD];         // 16.8 KB  (full logits for top-k)

#pragma unroll
    for (int r = 0; r < 4; ++r) {
        // each thread (wave wv, expert lane) deposits 16 row-partials
#pragma unroll
        for (int tp = 0; tp < 16; ++tp)
            stage[wv][tp][lane] = acc[r * 16 + tp];
        __syncthreads();
        {
            const int tp = tid >> 5;          // 0..15 row within group
            const int e0 = (tid & 31) * 2;    // 2 experts per thread
            float s0 = 0.f, s1 = 0.f;
#pragma unroll
            for (int u = 0; u < NWAVE; ++u) {
                s0 += stage[u][tp][e0];
                s1 += stage[u][tp][e0 + 1];
            }
            const int row = rowbase + r * 16 + tp;
            out_log[(size_t)row * NEXP + e0]     = s0;
            out_log[(size_t)row * NEXP + e0 + 1] = s1;
            lsmem[r * 16 + tp][e0]     = s0;
            lsmem[r * 16 + tp][e0 + 1] = s1;
        }
        __syncthreads();
    }

    // ---- top-2 + softmax: one row per thread (threads 0..63) ----
    if (tid < RPB) {
        const int row = rowbase + tid;
        float v1 = -INFINITY, v2 = -INFINITY;
        int i1 = 0, i2 = 0;
#pragma unroll 1
        for (int e = 0; e < NEXP; ++e) {
            float v = lsmem[tid][e];
            if (v > v1)      { v2 = v1; i2 = i1; v1 = v; i1 = e; }
            else if (v > v2) { v2 = v;  i2 = e; }
        }
        float ew    = expf(v2 - v1);       // <= 1, no overflow
        float denom = 1.f / (1.f + ew);
        out_idx[row * 2]     = (float)i1;
        out_idx[row * 2 + 1] = (float)i2;
        out_wgt[row * 2]     = denom;
        out_wgt[row * 2 + 1] = ew * denom;
    }
}

extern "C" void kernel_launch(void* const* d_in, const int* in_sizes, int n_in,
                              void* d_out, int out_size, void* d_ws, size_t ws_size,
                              hipStream_t stream)
{
    const float* x = (const float*)d_in[0];
    const float* W = (const float*)d_in[1];
    float* out = (float*)d_out;
    dim3 grid(NROWS / RPB);   // 512 blocks
    dim3 block(512);          // 8 waves
    hipLaunchKernelGGL(router_kernel, grid, block, 0, stream, x, W, out);
}

// Round 2
// 569.653 us; speedup vs baseline: 1.4907x; 1.4907x over previous
//
#include <hip/hip_runtime.h>
#include <math.h>

#define NROWS 32768
#define NEMBD 2048
#define NEXP  64
#define RPB   32                 // rows per block
#define NWAVE 8                  // waves per block = split-K factor
#define KSLICE (NEMBD / NWAVE)   // 256 k per wave
#define KCH   16                 // k-chunk per W register tile
#define RG    16                 // rows per accumulation pass (acc fits regs!)
#define NPASS (RPB / RG)         // 2

__global__ __launch_bounds__(512, 8)
void router_kernel(const float* __restrict__ x,
                   const float* __restrict__ W,
                   float* __restrict__ out)
{
    float* out_idx = out;                 // [32768][2] indices (as float)
    float* out_wgt = out + 2 * NROWS;     // [32768][2] softmax weights
    float* out_log = out + 4 * NROWS;     // [32768][64] logits

    const int tid  = threadIdx.x;
    const int lane = tid & 63;                                   // expert id
    const int wv   = __builtin_amdgcn_readfirstlane(tid >> 6);   // k-slice id
    const int rowbase = blockIdx.x * RPB;

    // per-lane: this lane's expert row, this wave's K-slice (L1/L2-hot)
    const float* __restrict__ Wl = W + (size_t)lane * NEMBD + wv * KSLICE;

    __shared__ float stage[NWAVE][RG][NEXP];   // 32 KB -> 4 blocks/CU

#pragma unroll 1
    for (int rg = 0; rg < NPASS; ++rg) {
        // wave-uniform x base -> scalar (s_load) path
        const float* __restrict__ xbase =
            x + (size_t)(rowbase + rg * RG) * NEMBD + wv * KSLICE;

        float acc[RG];
#pragma unroll
        for (int t = 0; t < RG; ++t) acc[t] = 0.f;

#pragma unroll 1
        for (int k0 = 0; k0 < KSLICE; k0 += KCH) {
            // W chunk -> VGPRs, reused across the 16 rows
            float wreg[KCH];
#pragma unroll
            for (int j = 0; j < KCH; j += 4) {
                float4 v = *reinterpret_cast<const float4*>(Wl + k0 + j);
                wreg[j+0] = v.x; wreg[j+1] = v.y; wreg[j+2] = v.z; wreg[j+3] = v.w;
            }
            // x values wave-uniform -> SGPR; inner op: v_fmac_f32 acc, s, v
#pragma unroll
            for (int t = 0; t < RG; ++t) {
                const float* xr = xbase + (size_t)t * NEMBD + k0;
                float a = acc[t];
#pragma unroll
                for (int j = 0; j < KCH; ++j)
                    a = fmaf(xr[j], wreg[j], a);
                acc[t] = a;
            }
        }

        if (rg) __syncthreads();   // previous pass's readers must finish
#pragma unroll
        for (int t = 0; t < RG; ++t)
            stage[wv][t][lane] = acc[t];          // lane-consecutive: conflict-free
        __syncthreads();

        // split-K reduce + top-2: wave wv owns rows {wv, wv+8} of this pass;
        // after the reduce, a row's 64 expert logits sit in one wave's 64 lanes.
#pragma unroll
        for (int half = 0; half < 2; ++half) {
            const int tp  = wv + half * NWAVE;
            const int row = rowbase + rg * RG + tp;

            float s = 0.f;
#pragma unroll
            for (int u = 0; u < NWAVE; ++u)
                s += stage[u][tp][lane];          // lane-consecutive: conflict-free

            out_log[(size_t)row * NEXP + lane] = s;   // 256B coalesced per wave

            // wave-wide argmax (ties -> smallest index, matches stable argsort)
            float v1 = s; int i1 = lane;
#pragma unroll
            for (int d = 32; d >= 1; d >>= 1) {
                float ov = __shfl_xor(v1, d, 64);
                int   oi = __shfl_xor(i1, d, 64);
                if (ov > v1 || (ov == v1 && oi < i1)) { v1 = ov; i1 = oi; }
            }
            // second max, excluding i1
            float v2 = (lane == i1) ? -INFINITY : s; int i2 = lane;
#pragma unroll
            for (int d = 32; d >= 1; d >>= 1) {
                float ov = __shfl_xor(v2, d, 64);
                int   oi = __shfl_xor(i2, d, 64);
                if (ov > v2 || (ov == v2 && oi < i2)) { v2 = ov; i2 = oi; }
            }

            if (lane == 0) {
                float ew = expf(v2 - v1);          // <= 1, no overflow
                float dn = 1.f / (1.f + ew);
                out_idx[row * 2]     = (float)i1;
                out_idx[row * 2 + 1] = (float)i2;
                out_wgt[row * 2]     = dn;
                out_wgt[row * 2 + 1] = ew * dn;
            }
        }
    }
}

extern "C" void kernel_launch(void* const* d_in, const int* in_sizes, int n_in,
                              void* d_out, int out_size, void* d_ws, size_t ws_size,
                              hipStream_t stream)
{
    const float* x = (const float*)d_in[0];
    const float* W = (const float*)d_in[1];
    float* out = (float*)d_out;
    dim3 grid(NROWS / RPB);   // 1024 blocks -> 4 per CU
    dim3 block(512);          // 8 waves
    hipLaunchKernelGGL(router_kernel, grid, block, 0, stream, x, W, out);
}